// Round 4
// baseline (128.818 us; speedup 1.0000x reference)
//
#include <hip/hip_runtime.h>
#include <math.h>

#define F 128
#define H 64       // F/2
#define NBMOL 48
#define ATB 16     // atoms per block in atom kernel (8 per wave, 1 net)
#define CAP 256    // LDS chunk capacity in pair kernel
#define SPLIT 16   // blocks per molecule in pair kernel

__device__ __forceinline__ float silu_f(float x) {
    return x / (1.0f + __expf(-x));
}
__device__ __forceinline__ float softplus_f(float x) {
    return fmaxf(x, 0.0f) + log1pf(__expf(-fabsf(x)));
}
__device__ __forceinline__ float frcp(float x) {
    return __builtin_amdgcn_rcpf(x);
}

// Kernel A v4: wave = 8 atoms x ONE net; lane = hidden unit j.
// Weight column W1[:,lane] held in 128 VGPRs (loaded once, coalesced, no LDS,
// no barrier). Activations via broadcast global_load_dwordx4 (vmcnt-pipelined
// across iterations; avoids the lgkmcnt(0)-drain serialization of s_load/LDS).
// Dipole: half-wave float4 dot, h1 streamed fully coalesced dwordx4.
__global__ __launch_bounds__(256, 2) void k_atom(
    const float* __restrict__ h0, const float* __restrict__ h1,
    const int* __restrict__ batch,
    const float* __restrict__ qW1, const float* __restrict__ qb1,
    const float* __restrict__ qW2, const float* __restrict__ qb2,
    const float* __restrict__ cW1, const float* __restrict__ cb1,
    const float* __restrict__ cW2, const float* __restrict__ cb2,
    const float* __restrict__ muW,
    float* __restrict__ q_raw, float* __restrict__ sqc6,
    float* __restrict__ mu,
    int* __restrict__ segstart, int* __restrict__ segend,
    float* __restrict__ out, int N)
{
    const int tid = threadIdx.x;
    if (blockIdx.x == 0 && tid == 0) out[0] = 0.0f;

    const int lane = tid & 63;
    const int w = tid >> 6;          // wave 0..3
    const int net = w & 1;           // 0 = charge, 1 = c6
    const int grp = w >> 1;          // atom group 0..1 (8 atoms each)
    int a0 = __builtin_amdgcn_readfirstlane(blockIdx.x * ATB + grp * 8);

    const float* __restrict__ W1 = net ? cW1 : qW1;
    const float* __restrict__ b1 = net ? cb1 : qb1;
    const float* __restrict__ W2 = net ? cW2 : qW2;

    // ---- weight column into VGPRs (128 coalesced, independent loads) ----
    float wreg[F];
    #pragma unroll
    for (int f = 0; f < F; ++f) wreg[f] = W1[f * H + lane];

    // ---- MLP hidden layer: 8 atoms, broadcast x, vmcnt-pipelined ----
    const float4* __restrict__ r[8];
    #pragma unroll
    for (int a = 0; a < 8; ++a)
        r[a] = (const float4*)(h0 + (size_t)min(a0 + a, N - 1) * F);

    float acc[8];
    {
        float b = b1[lane];
        #pragma unroll
        for (int a = 0; a < 8; ++a) acc[a] = b;
    }

    #pragma unroll
    for (int fb = 0; fb < F / 4; ++fb) {
        #pragma unroll
        for (int a = 0; a < 8; ++a) {
            float4 x = r[a][fb];
            acc[a] = fmaf(x.x, wreg[4 * fb + 0],
                     fmaf(x.y, wreg[4 * fb + 1],
                     fmaf(x.z, wreg[4 * fb + 2],
                     fmaf(x.w, wreg[4 * fb + 3], acc[a]))));
        }
    }

    const float w2 = W2[lane];
    float v[8];
    #pragma unroll
    for (int a = 0; a < 8; ++a) v[a] = silu_f(acc[a]) * w2;

    #pragma unroll
    for (int off = 32; off > 0; off >>= 1) {
        #pragma unroll
        for (int a = 0; a < 8; ++a) v[a] += __shfl_xor(v[a], off);
    }

    const float b2v = net ? cb2[0] : qb2[0];
    #pragma unroll
    for (int a = 0; a < 8; ++a) {
        if (lane == a) {
            int i = a0 + a;
            if (i < N) {
                float s = v[a] + b2v;
                if (net == 0) {
                    q_raw[i] = s;
                    int b = batch[i];
                    if (i == 0 || batch[i - 1] != b) segstart[b] = i;
                    if (i == N - 1 || batch[i + 1] != b) segend[b] = i + 1;
                } else {
                    sqc6[i] = sqrtf(softplus_f(s));
                }
            }
        }
    }

    // ---- dipole: 48 rows/block (16 atoms x 3), 12 per wave, 2 per step ----
    // half-wave hl reads row as 32 float4 (fully coalesced dwordx4 stream)
    const int hw = lane >> 5;   // half-wave 0/1
    const int hl = lane & 31;
    const float4 mw4 = ((const float4*)muW)[hl];
    const int rbase = blockIdx.x * (ATB * 3) + w * 12;
    #pragma unroll
    for (int s = 0; s < 6; ++s) {
        int row = rbase + s * 2 + hw;           // flat (i*3+d) row of h1
        if (row < 3 * N) {
            const float4* rp = (const float4*)(h1 + (size_t)row * F);
            float4 hv = rp[hl];
            float pm = fmaf(hv.x, mw4.x, fmaf(hv.y, mw4.y,
                       fmaf(hv.z, mw4.z, hv.w * mw4.w)));
            #pragma unroll
            for (int off = 16; off > 0; off >>= 1) pm += __shfl_xor(pm, off);
            if (hl == 0) mu[row] = pm;
        }
    }
}

// Kernel B v4: pairwise energy. Grid (NBMOL, SPLIT); block 256.
// Staging does NOT depend on the mean (mean subtracted per-pair), so the
// mean-reduce overlaps the SoA staging. pos/mu packed stride-3 (odd stride
// -> conflict-free LDS).
__global__ __launch_bounds__(256) void k_pair(
    const float* __restrict__ pos,
    const float* __restrict__ q_raw, const float* __restrict__ sqc6,
    const float* __restrict__ mu,
    const int* __restrict__ segstart, const int* __restrict__ segend,
    float* __restrict__ out)
{
    const int b = blockIdx.x;
    const int s = blockIdx.y;
    const int tid = threadIdx.x;
    const int st = segstart[b];
    const int n = segend[b] - st;

    __shared__ float sq[CAP], sc[CAP], sp[3 * CAP], sm[3 * CAP];
    __shared__ float red[4];

    float e_c = 0.f, e_v = 0.f, e_d = 0.f;

    if (n > 1 && n <= CAP) {
        // stage + accumulate mean partial in one pass
        float part = 0.f;
        for (int k = tid; k < n; k += 256) {
            float qv = q_raw[st + k];
            sq[k] = qv; part += qv;
            sc[k] = sqc6[st + k];
        }
        for (int k = tid; k < 3 * n; k += 256) {
            sp[k] = pos[3 * st + k];
            sm[k] = mu[3 * st + k];
        }
        #pragma unroll
        for (int off = 32; off > 0; off >>= 1) part += __shfl_xor(part, off);
        if ((tid & 63) == 0) red[tid >> 6] = part;
        __syncthreads();
        const float mean = (red[0] + red[1] + red[2] + red[3]) / (float)n;

        const int r = tid >> 4;   // row slot 0..15
        const int c = tid & 15;   // col lane 0..15
        for (int il = s + SPLIT * r; il < n; il += SPLIT * 16) {
            const float qi = sq[il] - mean;
            const float sci = sc[il];
            const float xi = sp[3 * il], yi = sp[3 * il + 1], zi = sp[3 * il + 2];
            const float mxi = sm[3 * il], myi = sm[3 * il + 1], mzi = sm[3 * il + 2];
            for (int jl = c; jl < n; jl += 16) {
                if (jl == il) continue;
                float dx = xi - sp[3 * jl], dy = yi - sp[3 * jl + 1],
                      dz = zi - sp[3 * jl + 2];
                float ds0 = fmaf(dx, dx, fmaf(dy, dy, dz * dz));
                float d = sqrtf(ds0 + 1e-8f);
                float inv_d = frcp(d);
                float qj = sq[jl] - mean;
                e_c = fmaf(qi * qj * inv_d, 1.0f - __expf(-0.5f * d), e_c);
                float r6 = ds0 * ds0 * ds0;
                e_v = fmaf(sci * sc[jl], frcp(r6 + 20.0f), e_v);
                float smx = sm[3 * jl], smy = sm[3 * jl + 1], smz = sm[3 * jl + 2];
                float mdm = fmaf(mxi, smx, fmaf(myi, smy, mzi * smz));
                float mdni = fmaf(mxi, dx, fmaf(myi, dy, mzi * dz)) * inv_d;
                float mdnj = fmaf(smx, dx, fmaf(smy, dy, smz * dz)) * inv_d;
                e_d = fmaf(mdm - 3.0f * mdni * mdnj,
                           frcp(fmaf(ds0, d, 10.0f)), e_d);
            }
        }
    } else if (n > CAP) {
        // generic chunked fallback (never hit at N/NB ~ 128, kept for safety)
        float part = 0.f;
        for (int k = tid; k < n; k += 256) part += q_raw[st + k];
        #pragma unroll
        for (int off = 32; off > 0; off >>= 1) part += __shfl_xor(part, off);
        if ((tid & 63) == 0) red[tid >> 6] = part;
        __syncthreads();
        const float mean = (red[0] + red[1] + red[2] + red[3]) / (float)n;
        const int r = tid >> 4, c = tid & 15;
        for (int j0 = 0; j0 < n; j0 += CAP) {
            const int chunk = min(CAP, n - j0);
            __syncthreads();
            for (int k = tid; k < chunk; k += 256) {
                sq[k] = q_raw[st + j0 + k];
                sc[k] = sqc6[st + j0 + k];
            }
            for (int k = tid; k < 3 * chunk; k += 256) {
                sp[k] = pos[3 * (st + j0) + k];
                sm[k] = mu[3 * (st + j0) + k];
            }
            __syncthreads();
            for (int il = s + SPLIT * r; il < n; il += SPLIT * 16) {
                const int i = st + il;
                const float qi = q_raw[i] - mean;
                const float sci = sqc6[i];
                const float xi = pos[i * 3], yi = pos[i * 3 + 1], zi = pos[i * 3 + 2];
                const float mxi = mu[i * 3], myi = mu[i * 3 + 1], mzi = mu[i * 3 + 2];
                for (int jl = c; jl < chunk; jl += 16) {
                    if (j0 + jl == il) continue;
                    float dx = xi - sp[3 * jl], dy = yi - sp[3 * jl + 1],
                          dz = zi - sp[3 * jl + 2];
                    float ds0 = fmaf(dx, dx, fmaf(dy, dy, dz * dz));
                    float d = sqrtf(ds0 + 1e-8f);
                    float inv_d = frcp(d);
                    float qj = sq[jl] - mean;
                    e_c = fmaf(qi * qj * inv_d, 1.0f - __expf(-0.5f * d), e_c);
                    float r6 = ds0 * ds0 * ds0;
                    e_v = fmaf(sci * sc[jl], frcp(r6 + 20.0f), e_v);
                    float smx = sm[3 * jl], smy = sm[3 * jl + 1], smz = sm[3 * jl + 2];
                    float mdm = fmaf(mxi, smx, fmaf(myi, smy, mzi * smz));
                    float mdni = fmaf(mxi, dx, fmaf(myi, dy, mzi * dz)) * inv_d;
                    float mdnj = fmaf(smx, dx, fmaf(smy, dy, smz * dz)) * inv_d;
                    e_d = fmaf(mdm - 3.0f * mdni * mdnj,
                               frcp(fmaf(ds0, d, 10.0f)), e_d);
                }
            }
        }
    }

    // energy = 0.5*14.399*E_coul - 0.5*E_vdw_mag + 0.5*E_dip
    float vv = fmaf(7.1995f, e_c, fmaf(-0.5f, e_v, 0.5f * e_d));
    #pragma unroll
    for (int off = 32; off > 0; off >>= 1) vv += __shfl_xor(vv, off);
    __syncthreads();
    if ((tid & 63) == 0) red[tid >> 6] = vv;
    __syncthreads();
    if (tid == 0) atomicAdd(out, red[0] + red[1] + red[2] + red[3]);
}

extern "C" void kernel_launch(void* const* d_in, const int* in_sizes, int n_in,
                              void* d_out, int out_size, void* d_ws, size_t ws_size,
                              hipStream_t stream) {
    const float* h0  = (const float*)d_in[0];
    const float* h1  = (const float*)d_in[1];
    const float* pos = (const float*)d_in[2];
    const int*   batch = (const int*)d_in[3];
    const float* qW1 = (const float*)d_in[4];
    const float* qb1 = (const float*)d_in[5];
    const float* qW2 = (const float*)d_in[6];
    const float* qb2 = (const float*)d_in[7];
    const float* cW1 = (const float*)d_in[8];
    const float* cb1 = (const float*)d_in[9];
    const float* cW2 = (const float*)d_in[10];
    const float* cb2 = (const float*)d_in[11];
    const float* muW = (const float*)d_in[12];
    float* out = (float*)d_out;
    const int N = in_sizes[0] / F;

    // workspace layout (floats): [segstart 48 | segend 48 | pad to 128 |
    //                             q_raw N | sqc6 N | mu 3N]
    float* ws = (float*)d_ws;
    int* segstart = (int*)ws;
    int* segend   = (int*)(ws + 48);
    float* q_raw = ws + 128;
    float* sqc6  = q_raw + N;
    float* mu    = sqc6 + N;

    int nblk = (N + ATB - 1) / ATB;
    k_atom<<<nblk, 256, 0, stream>>>(h0, h1, batch, qW1, qb1, qW2, qb2,
                                     cW1, cb1, cW2, cb2, muW,
                                     q_raw, sqc6, mu, segstart, segend,
                                     out, N);
    k_pair<<<dim3(NBMOL, SPLIT), 256, 0, stream>>>(pos, q_raw, sqc6, mu,
                                                   segstart, segend, out);
}